// Round 1
// baseline (6556.841 us; speedup 1.0000x reference)
//
#include <hip/hip_runtime.h>
#include <stdint.h>

// Llama-ish forward: B=2 S=2048 D=2048 NL=4 NH=16 NKV=4 HD=128 FH=5504 V=32000
#define DD     2048
#define NLAYER 4
#define NHEAD  16
#define NKVH   4
#define HDIM   128
#define FHID   5504
#define VOCAB  32000
#define BATCH  2
#define SEQ    2048
#define MR     (BATCH*SEQ)   // 4096 activation rows
#define RMS_EPS 1e-5f

typedef __bf16 bf16x8 __attribute__((ext_vector_type(8)));
typedef float  f32x4  __attribute__((ext_vector_type(4)));

typedef const __attribute__((address_space(1))) void* gas1_t;
typedef __attribute__((address_space(3))) void* las3_t;

__device__ __forceinline__ void gld16(const ushort* g, ushort* l) {
  __builtin_amdgcn_global_load_lds((gas1_t)g, (las3_t)l, 16, 0, 0);
}

__device__ __forceinline__ ushort f2bf(float f) {
  uint32_t u = __builtin_bit_cast(uint32_t, f);
  u += 0x7fffu + ((u >> 16) & 1u);   // RNE
  return (ushort)(u >> 16);
}
__device__ __forceinline__ float bf2f(ushort h) {
  uint32_t u = ((uint32_t)h) << 16;
  return __builtin_bit_cast(float, u);
}

// ---------------- GEMM: C[M,N] = A[M,K] @ Bt[N,K]^T (+res), bf16 MFMA ----------
// 128x128 tile, BK=32, 256 thr (4 waves, 2x2 of 64x64), m97 structure.
// Batched z: offA = z*sAz_l + zg*sAz_g ; zg = z+z0
//            offB = (zg>>4)*sB_b + ((zg&15)>>2)*sB_h   (b / kv-head mapping)
//            offC = z*sCz_l + (zg>>4)*sC_b + (zg&15)*sC_h
__global__ __launch_bounds__(256) void gemm_bt_kernel(
    const ushort* __restrict__ A, const ushort* __restrict__ Bt,
    float* __restrict__ Cf, ushort* __restrict__ Cb,
    const float* __restrict__ Res,
    int K, int ldA, int ldB, int ldC,
    long sAz_l, long sAz_g, long sB_b, long sB_h,
    long sCz_l, long sC_b, long sC_h, int z0)
{
  __shared__ alignas(16) ushort As[128*32];
  __shared__ alignas(16) ushort Bs[128*32];
  const int tid  = threadIdx.x;
  const int wave = tid >> 6, lane = tid & 63;
  const int wr = wave >> 1, wc = wave & 1;
  const int quad = lane >> 4, lr = lane & 15;
  const int z = blockIdx.z, zg = z + z0;
  const long offA = (long)z*sAz_l + (long)zg*sAz_g;
  const long offB = (long)(zg>>4)*sB_b + (long)((zg&15)>>2)*sB_h;
  const long offC = (long)z*sCz_l + (long)(zg>>4)*sC_b + (long)(zg&15)*sC_h;
  const int m0 = blockIdx.y*128, n0 = blockIdx.x*128;

  const ushort* Ag = A  + offA + (size_t)(m0 + wave*32 + (lane>>2))*ldA + (lane&3)*8;
  const ushort* Bg = Bt + offB + (size_t)(n0 + wave*32 + (lane>>2))*ldB + (lane&3)*8;
  ushort* Asw = &As[wave*32*32 + lane*8];
  ushort* Bsw = &Bs[wave*32*32 + lane*8];

  f32x4 acc[4][4];
  #pragma unroll
  for (int i=0;i<4;i++)
    #pragma unroll
    for (int j=0;j<4;j++)
      acc[i][j] = (f32x4){0.f,0.f,0.f,0.f};

  const int nk = K >> 5;
  for (int kk=0; kk<nk; ++kk) {
    __syncthreads();                    // LDS free from previous iter
    gld16(Ag,                  Asw);
    gld16(Ag + 16*(size_t)ldA, Asw + 16*32);
    gld16(Bg,                  Bsw);
    gld16(Bg + 16*(size_t)ldB, Bsw + 16*32);
    Ag += 32; Bg += 32;
    __syncthreads();                    // drains vmcnt -> tiles visible
    bf16x8 af[4], bfr[4];
    #pragma unroll
    for (int i=0;i<4;i++)
      af[i]  = *(const bf16x8*)&As[(wr*64 + i*16 + lr)*32 + quad*8];
    #pragma unroll
    for (int j=0;j<4;j++)
      bfr[j] = *(const bf16x8*)&Bs[(wc*64 + j*16 + lr)*32 + quad*8];
    #pragma unroll
    for (int i=0;i<4;i++)
      #pragma unroll
      for (int j=0;j<4;j++)
        acc[i][j] = __builtin_amdgcn_mfma_f32_16x16x32_bf16(af[i], bfr[j], acc[i][j], 0, 0, 0);
  }

  #pragma unroll
  for (int i=0;i<4;i++)
    #pragma unroll
    for (int j=0;j<4;j++)
      #pragma unroll
      for (int r=0;r<4;r++) {
        const int row = m0 + wr*64 + i*16 + quad*4 + r;   // C/D: row=quad*4+reg
        const int col = n0 + wc*64 + j*16 + lr;           //      col=lane&15
        const size_t idx = (size_t)offC + (size_t)row*ldC + col;
        float v = acc[i][j][r];
        if (Res) v += Res[idx];
        if (Cb) Cb[idx] = f2bf(v);
        else    Cf[idx] = v;
      }
}

// ---------------- weight transpose-convert: fp32 [z][R][C] -> bf16 [z][C][R] ---
__global__ __launch_bounds__(256) void transpose_convert_kernel(
    const float* __restrict__ in, ushort* __restrict__ out,
    int R, int C, long inStride, long outStride)
{
  __shared__ float t[32][33];
  const int z = blockIdx.z;
  const float* I = in + (size_t)z*inStride;
  ushort* O = out + (size_t)z*outStride;
  const int c0 = blockIdx.x*32, r0 = blockIdx.y*32;
  const int tx = threadIdx.x, ty = threadIdx.y;  // (32,8)
  #pragma unroll
  for (int j=0;j<4;j++)
    t[ty+j*8][tx] = I[(size_t)(r0+ty+j*8)*C + c0+tx];
  __syncthreads();
  #pragma unroll
  for (int j=0;j<4;j++)
    O[(size_t)(c0+ty+j*8)*R + r0+tx] = f2bf(t[tx][ty+j*8]);
}

// ---------------- V transpose: v fp32 [4096][512] -> Vt bf16 [b*4+kv][128][2048]
__global__ __launch_bounds__(256) void vtrans_kernel(
    const float* __restrict__ v, ushort* __restrict__ vt)
{
  __shared__ float t[32][33];
  const int z = blockIdx.z, b = z >> 2, kv = z & 3;
  const int s0 = blockIdx.x*32, d0 = blockIdx.y*32;
  const int tx = threadIdx.x, ty = threadIdx.y;  // (32,8)
  const float* I = v + (size_t)b*SEQ*(NKVH*HDIM) + (size_t)kv*HDIM;
  #pragma unroll
  for (int j=0;j<4;j++)
    t[ty+j*8][tx] = I[(size_t)(s0+ty+j*8)*(NKVH*HDIM) + d0+tx];
  __syncthreads();
  ushort* O = vt + (size_t)z*HDIM*SEQ;
  #pragma unroll
  for (int j=0;j<4;j++)
    O[(size_t)(d0+ty+j*8)*SEQ + s0+tx] = f2bf(t[tx][ty+j*8]);
}

// ---------------- embedding gather --------------------------------------------
__global__ __launch_bounds__(256) void embed_kernel(
    const int* __restrict__ tok, const float* __restrict__ emb, float* __restrict__ h)
{
  const int row = blockIdx.x;
  const int t = tok[row];
  const float4* src = (const float4*)(emb + (size_t)t*DD);
  float4* dst = (float4*)(h + (size_t)row*DD);
  dst[threadIdx.x]       = src[threadIdx.x];
  dst[threadIdx.x + 256] = src[threadIdx.x + 256];
}

// ---------------- RMSNorm fp32 -> bf16 -----------------------------------------
__global__ __launch_bounds__(256) void rmsnorm_kernel(
    const float* __restrict__ x, const float* __restrict__ w, ushort* __restrict__ out)
{
  const int row = blockIdx.x, tid = threadIdx.x;
  const float4* xr = (const float4*)(x + (size_t)row*DD);
  float4 a = xr[tid], b = xr[tid+256];
  float ss = a.x*a.x+a.y*a.y+a.z*a.z+a.w*a.w
           + b.x*b.x+b.y*b.y+b.z*b.z+b.w*b.w;
  #pragma unroll
  for (int o=32;o>0;o>>=1) ss += __shfl_down(ss, o);
  __shared__ float red[4];
  if ((tid&63)==0) red[tid>>6] = ss;
  __syncthreads();
  const float tot = red[0]+red[1]+red[2]+red[3];
  const float sc = rsqrtf(tot*(1.0f/DD) + RMS_EPS);
  const float4* w4 = (const float4*)w;
  float4 wa = w4[tid], wb = w4[tid+256];
  ushort4 oa, ob;
  oa.x=f2bf(a.x*sc*wa.x); oa.y=f2bf(a.y*sc*wa.y); oa.z=f2bf(a.z*sc*wa.z); oa.w=f2bf(a.w*sc*wa.w);
  ob.x=f2bf(b.x*sc*wb.x); ob.y=f2bf(b.y*sc*wb.y); ob.z=f2bf(b.z*sc*wb.z); ob.w=f2bf(b.w*sc*wb.w);
  ushort4* o4 = (ushort4*)(out + (size_t)row*DD);
  o4[tid] = oa; o4[tid+256] = ob;
}

// ---------------- RoPE: fp32 [4096][nh*128] -> bf16 [b][h][s][128] -------------
__global__ void rope_kernel(const float* __restrict__ x, ushort* __restrict__ out, int nheads)
{
  const int row = blockIdx.x;        // b*SEQ + s
  const int h = blockIdx.y;
  const int i = threadIdx.x;         // 0..63 pair index
  const int b = row >> 11, s = row & (SEQ-1);
  const float inv = expf(-(float)i * 0.2050369277719426f); // ln(5e5)/64
  const float ang = (float)s * inv;
  float sn, cs;
  sincosf(ang, &sn, &cs);
  const size_t ib = (size_t)row*(nheads*HDIM) + (size_t)h*HDIM + 2*i;
  const float xr = x[ib], xi = x[ib+1];
  const size_t ob = (((size_t)(b*nheads + h))*SEQ + s)*HDIM + 2*i;
  out[ob]   = f2bf(xr*cs - xi*sn);
  out[ob+1] = f2bf(xr*sn + xi*cs);
}

// ---------------- causal softmax, in-place on bf16 scores ----------------------
__global__ __launch_bounds__(256) void softmax_kernel(ushort* __restrict__ Sc)
{
  const int q = blockIdx.x, zc = blockIdx.y, tid = threadIdx.x;
  const size_t base = ((size_t)zc*SEQ + q)*SEQ;
  const float scale = 0.08838834764831845f;  // 1/sqrt(128)
  float t[8];
  float m = -1e30f;
  #pragma unroll
  for (int i=0;i<8;i++) {
    const int c = i*256 + tid;
    const float val = bf2f(Sc[base+c]) * scale;
    t[i] = (c <= q) ? val : -1e30f;
    m = fmaxf(m, t[i]);
  }
  #pragma unroll
  for (int o=32;o>0;o>>=1) m = fmaxf(m, __shfl_down(m, o));
  __shared__ float red[4];
  if ((tid&63)==0) red[tid>>6] = m;
  __syncthreads();
  m = fmaxf(fmaxf(red[0],red[1]), fmaxf(red[2],red[3]));
  float sum = 0.f;
  #pragma unroll
  for (int i=0;i<8;i++) {
    const int c = i*256 + tid;
    const float p = (c <= q) ? expf(t[i]-m) : 0.f;
    t[i] = p; sum += p;
  }
  #pragma unroll
  for (int o=32;o>0;o>>=1) sum += __shfl_down(sum, o);
  __syncthreads();
  if ((tid&63)==0) red[tid>>6] = sum;
  __syncthreads();
  const float invs = 1.f/(red[0]+red[1]+red[2]+red[3]);
  #pragma unroll
  for (int i=0;i<8;i++) Sc[base + i*256 + tid] = f2bf(t[i]*invs);
}

// ---------------- silu(x1)*x3 -> bf16 ------------------------------------------
__global__ __launch_bounds__(256) void silu_kernel(
    const ushort* __restrict__ x1, const ushort* __restrict__ x3,
    ushort* __restrict__ e, long n)
{
  long i = (long)blockIdx.x*256 + threadIdx.x;
  const long stride = (long)gridDim.x*256;
  for (; i < n; i += stride) {
    const float a = bf2f(x1[i]);
    const float b = bf2f(x3[i]);
    const float s = a / (1.f + expf(-a));
    e[i] = f2bf(s*b);
  }
}

// ---------------- host side ----------------------------------------------------
static inline void launch_gemm(hipStream_t st, const ushort* A, const ushort* Bt,
    float* Cf, ushort* Cb, const float* Res, int M, int N, int K,
    int ldA, int ldB, int ldC, int Z = 1,
    long sAz_l=0, long sAz_g=0, long sB_b=0, long sB_h=0,
    long sCz_l=0, long sC_b=0, long sC_h=0, int z0=0)
{
  gemm_bt_kernel<<<dim3(N/128, M/128, Z), 256, 0, st>>>(
      A, Bt, Cf, Cb, Res, K, ldA, ldB, ldC,
      sAz_l, sAz_g, sB_b, sB_h, sCz_l, sC_b, sC_h, z0);
}

static inline void transposeW(hipStream_t st, const float* in, ushort* out,
                              int R, int C, int nz)
{
  transpose_convert_kernel<<<dim3(C/32, R/32, nz), dim3(32,8), 0, st>>>(
      in, out, R, C, (long)R*C, (long)R*C);
}

extern "C" void kernel_launch(void* const* d_in, const int* in_sizes, int n_in,
                              void* d_out, int out_size, void* d_ws, size_t ws_size,
                              hipStream_t stream)
{
  const int*   tokens  = (const int*)d_in[0];
  const float* tok_emb = (const float*)d_in[2];
  const float* wq   = (const float*)d_in[3];
  const float* wk   = (const float*)d_in[4];
  const float* wv   = (const float*)d_in[5];
  const float* wo   = (const float*)d_in[6];
  const float* w1   = (const float*)d_in[7];
  const float* w2   = (const float*)d_in[8];
  const float* w3   = (const float*)d_in[9];
  const float* anw  = (const float*)d_in[10];
  const float* fnw  = (const float*)d_in[11];
  const float* finw = (const float*)d_in[12];
  const float* outw = (const float*)d_in[13];
  float* out = (float*)d_out;

  // carve workspace (256B aligned)
  char* p = (char*)d_ws;
  auto alloc = [&](size_t bytes) { char* r = p; p += (bytes + 255) & ~(size_t)255; return r; };
  ushort* wqT = (ushort*)alloc((size_t)NLAYER*DD*DD*2);
  ushort* wkT = (ushort*)alloc((size_t)NLAYER*NKVH*HDIM*DD*2);
  ushort* wvT = (ushort*)alloc((size_t)NLAYER*NKVH*HDIM*DD*2);
  ushort* woT = (ushort*)alloc((size_t)NLAYER*DD*DD*2);
  ushort* w1T = (ushort*)alloc((size_t)NLAYER*FHID*DD*2);
  ushort* w2T = (ushort*)alloc((size_t)NLAYER*DD*FHID*2);
  ushort* w3T = (ushort*)alloc((size_t)NLAYER*FHID*DD*2);
  ushort* owT = (ushort*)alloc((size_t)VOCAB*DD*2);
  float*  h   = (float*)alloc((size_t)MR*DD*4);
  ushort* xn  = (ushort*)alloc((size_t)MR*DD*2);
  float*  qf  = (float*)alloc((size_t)MR*DD*4);
  float*  kf  = (float*)alloc((size_t)MR*NKVH*HDIM*4);
  float*  vf  = (float*)alloc((size_t)MR*NKVH*HDIM*4);
  ushort* Qb  = (ushort*)alloc((size_t)MR*DD*2);
  ushort* Kb  = (ushort*)alloc((size_t)MR*NKVH*HDIM*2);
  ushort* Vt  = (ushort*)alloc((size_t)MR*NKVH*HDIM*2);
  ushort* ctx = (ushort*)alloc((size_t)MR*DD*2);
  ushort* x1b = (ushort*)alloc((size_t)MR*FHID*2);
  ushort* x3b = (ushort*)alloc((size_t)MR*FHID*2);
  ushort* eb  = (ushort*)alloc((size_t)MR*FHID*2);
  size_t used = (size_t)(p - (char*)d_ws);
  size_t rem = ws_size > used ? ws_size - used : 0;
  int CH = 32;                                   // heads per attention chunk
  while (CH > 1 && (size_t)CH*SEQ*SEQ*2 > rem) CH >>= 1;
  ushort* Sc = (ushort*)alloc((size_t)CH*SEQ*SEQ*2);

  // weight conversion (fp32 [K][N] -> bf16 [N][K])
  transposeW(stream, wq,   wqT, DD,   DD,        NLAYER);
  transposeW(stream, wk,   wkT, DD,   NKVH*HDIM, NLAYER);
  transposeW(stream, wv,   wvT, DD,   NKVH*HDIM, NLAYER);
  transposeW(stream, wo,   woT, DD,   DD,        NLAYER);
  transposeW(stream, w1,   w1T, DD,   FHID,      NLAYER);
  transposeW(stream, w2,   w2T, FHID, DD,        NLAYER);
  transposeW(stream, w3,   w3T, DD,   FHID,      NLAYER);
  transposeW(stream, outw, owT, DD,   VOCAB,     1);

  embed_kernel<<<MR, 256, 0, stream>>>(tokens, tok_emb, h);

  for (int l = 0; l < NLAYER; ++l) {
    rmsnorm_kernel<<<MR, 256, 0, stream>>>(h, anw + (size_t)l*DD, xn);
    launch_gemm(stream, xn, wqT + (size_t)l*DD*DD,        qf, nullptr, nullptr,
                MR, DD,        DD, DD, DD, DD);
    launch_gemm(stream, xn, wkT + (size_t)l*NKVH*HDIM*DD, kf, nullptr, nullptr,
                MR, NKVH*HDIM, DD, DD, DD, NKVH*HDIM);
    launch_gemm(stream, xn, wvT + (size_t)l*NKVH*HDIM*DD, vf, nullptr, nullptr,
                MR, NKVH*HDIM, DD, DD, DD, NKVH*HDIM);
    rope_kernel<<<dim3(MR, NHEAD), 64, 0, stream>>>(qf, Qb, NHEAD);
    rope_kernel<<<dim3(MR, NKVH),  64, 0, stream>>>(kf, Kb, NKVH);
    vtrans_kernel<<<dim3(SEQ/32, HDIM/32, BATCH*NKVH), dim3(32,8), 0, stream>>>(vf, Vt);

    for (int c0 = 0; c0 < BATCH*NHEAD; c0 += CH) {
      // scores = Q @ K^T  (bf16 out, raw; scale folded into softmax)
      launch_gemm(stream, Qb, Kb, nullptr, Sc, nullptr,
                  SEQ, SEQ, HDIM, HDIM, HDIM, SEQ, CH,
                  0, (long)SEQ*HDIM,
                  (long)NKVH*SEQ*HDIM, (long)SEQ*HDIM,
                  (long)SEQ*SEQ, 0, 0, c0);
      softmax_kernel<<<dim3(SEQ, CH), 256, 0, stream>>>(Sc);
      // ctx = P @ V
      launch_gemm(stream, Sc, Vt, nullptr, ctx, nullptr,
                  SEQ, HDIM, SEQ, SEQ, SEQ, DD, CH,
                  (long)SEQ*SEQ, 0,
                  (long)NKVH*HDIM*SEQ, (long)HDIM*SEQ,
                  0, (long)SEQ*DD, (long)HDIM, c0);
    }

    // h += ctx @ wo
    launch_gemm(stream, ctx, woT + (size_t)l*DD*DD, h, nullptr, h,
                MR, DD, DD, DD, DD, DD);

    rmsnorm_kernel<<<MR, 256, 0, stream>>>(h, fnw + (size_t)l*DD, xn);
    launch_gemm(stream, xn, w1T + (size_t)l*FHID*DD, nullptr, x1b, nullptr,
                MR, FHID, DD, DD, DD, FHID);
    launch_gemm(stream, xn, w3T + (size_t)l*FHID*DD, nullptr, x3b, nullptr,
                MR, FHID, DD, DD, DD, FHID);
    silu_kernel<<<4096, 256, 0, stream>>>(x1b, x3b, eb, (long)MR*FHID);
    // h += e @ w2
    launch_gemm(stream, eb, w2T + (size_t)l*DD*FHID, h, nullptr, h,
                MR, DD, FHID, FHID, FHID, DD);
  }

  rmsnorm_kernel<<<MR, 256, 0, stream>>>(h, finw, xn);
  launch_gemm(stream, xn, owT, out, nullptr, nullptr,
              MR, VOCAB, DD, DD, DD, VOCAB);
}